// Round 4
// baseline (110.660 us; speedup 1.0000x reference)
//
#include <hip/hip_runtime.h>
#include <math.h>

#define N_PTS 16384
#define TPB 256
#define BR 512                 // rows (pred) per block
#define BC 512                 // cols (gt) per block
#define NRC (N_PTS / BR)       // 32 row chunks
#define NCC (N_PTS / BC)       // 32 col chunks
#define INF 3.0e38f

typedef short bf16x8 __attribute__((ext_vector_type(8)));
typedef float f32x4 __attribute__((ext_vector_type(4)));

__device__ __forceinline__ unsigned short bf16_rne(float x) {
    unsigned u = __float_as_uint(x);
    unsigned r = u + 0x7FFFu + ((u >> 16) & 1u);
    return (unsigned short)(r >> 16);
}
__device__ __forceinline__ float ubf(unsigned short h) {
    return __uint_as_float(((unsigned)h) << 16);
}

// ws layout:
//   [0]                    : unsigned counter (poisoned 0xAAAAAAAA each launch)
//   [256 .. +2MB)          : float rowPart[NCC][N_PTS]   (min over col-chunk, per pred row)
//   [256+2MB .. +2MB)      : float colPart[NRC][N_PTS]   (min over row-chunk, per gt col)
//   [256+4MB .. +1KB)      : float2 blockPart[128]

// Each block: 512 pred rows x 512 gt cols. MFMA 16x16x32 bf16 with K-packing:
//   A row  = [-ph(3), -pl(3), -ph(3), -pl(3), 1, 1, 0, 0]   (hi/lo bf16 split of pred)
//   B col  = [ gh(3),  gh(3),  gl(3),  gl(3), wh, wl, 0, 0] (w = |g|^2/2, hi/lo split)
//   C-init = |p|^2/2 (fp32, per C-row)  =>  D = |p-g|^2 / 2  (exact to ~3e-5)
// D is symmetric => row-min feeds fwd chamfer, col-min feeds bwd chamfer.

__global__ __launch_bounds__(TPB) void pairs_mfma(const float* __restrict__ pred,
                                                  const float* __restrict__ gt,
                                                  float* __restrict__ rowPart,
                                                  float* __restrict__ colPart) {
    __shared__ bf16x8 ldsA[BR * 2];            // 16KB: 16 bf16 (K slots 0..15) per row
    __shared__ bf16x8 ldsB[BC * 2];            // 16KB
    __shared__ __align__(16) float p2lds[BR];  // 2KB : |p|^2/2
    __shared__ float colw[4 * BC];             // 8KB : per-wave col mins

    int tid = threadIdx.x;
    int lane = tid & 63;
    int wid = tid >> 6;
    int rc = blockIdx.x & (NRC - 1);
    int cc = blockIdx.x >> 5;

    // ---- pack A (pred rows) and B (gt cols) into LDS ----
    for (int k = tid; k < BR + BC; k += TPB) {
        bool isA = k < BR;
        int loc = isA ? k : k - BR;
        int gidx = isA ? (rc * BR + loc) : (cc * BC + loc);
        const float* p = (isA ? pred : gt) + (size_t)gidx * 6;
        float x = p[0], y = p[1], z = p[2];
        unsigned short xh = bf16_rne(x), yh = bf16_rne(y), zh = bf16_rne(z);
        unsigned short xl = bf16_rne(x - ubf(xh));
        unsigned short yl = bf16_rne(y - ubf(yh));
        unsigned short zl = bf16_rne(z - ubf(zh));
        float nrm = 0.5f * (x * x + y * y + z * z);
        union { unsigned short u[16]; bf16x8 v[2]; } pk;
        if (isA) {
            unsigned short nxh = xh ^ 0x8000u, nyh = yh ^ 0x8000u, nzh = zh ^ 0x8000u;
            unsigned short nxl = xl ^ 0x8000u, nyl = yl ^ 0x8000u, nzl = zl ^ 0x8000u;
            const unsigned short one = 0x3F80u;
            pk.u[0] = nxh; pk.u[1] = nyh; pk.u[2] = nzh;
            pk.u[3] = nxl; pk.u[4] = nyl; pk.u[5] = nzl;
            pk.u[6] = nxh; pk.u[7] = nyh; pk.u[8] = nzh;
            pk.u[9] = nxl; pk.u[10] = nyl; pk.u[11] = nzl;
            pk.u[12] = one; pk.u[13] = one; pk.u[14] = 0; pk.u[15] = 0;
            ldsA[loc * 2] = pk.v[0]; ldsA[loc * 2 + 1] = pk.v[1];
            p2lds[loc] = nrm;
        } else {
            unsigned short wh = bf16_rne(nrm);
            unsigned short wl = bf16_rne(nrm - ubf(wh));
            pk.u[0] = xh; pk.u[1] = yh; pk.u[2] = zh;
            pk.u[3] = xh; pk.u[4] = yh; pk.u[5] = zh;
            pk.u[6] = xl; pk.u[7] = yl; pk.u[8] = zl;
            pk.u[9] = xl; pk.u[10] = yl; pk.u[11] = zl;
            pk.u[12] = wh; pk.u[13] = wl; pk.u[14] = 0; pk.u[15] = 0;
            ldsB[loc * 2] = pk.v[0]; ldsB[loc * 2 + 1] = pk.v[1];
        }
    }
    for (int c = tid; c < 4 * BC; c += TPB) colw[c] = INF;
    __syncthreads();

    // ---- per-wave: 128 rows = 8 row-tiles; load A frags + C-init (p^2/2) ----
    const bf16x8 zf = {0, 0, 0, 0, 0, 0, 0, 0};
    bf16x8 afrag[8];
    f32x4 p2frag[8];
    f32x4 rm[8];
    int wrow0 = wid * 128;
#pragma unroll
    for (int t = 0; t < 8; t++) {
        afrag[t] = zf;
        if (lane < 32) afrag[t] = ldsA[(wrow0 + t * 16 + (lane & 15)) * 2 + (lane >> 4)];
        p2frag[t] = *(const f32x4*)&p2lds[wrow0 + t * 16 + 4 * (lane >> 4)];
        rm[t] = (f32x4){INF, INF, INF, INF};
    }

    // ---- main loop: 32 col-tiles of 16 ----
    for (int step = 0; step < BC / 16; step++) {
        int c15 = lane & 15;
        bf16x8 bfrag = zf;
        if (lane < 32) bfrag = ldsB[(step * 16 + c15) * 2 + (lane >> 4)];
        float cm = INF;
#pragma unroll
        for (int t = 0; t < 8; t++) {
            f32x4 d = __builtin_amdgcn_mfma_f32_16x16x32_bf16(afrag[t], bfrag, p2frag[t], 0, 0, 0);
            f32x4 r = rm[t];
            rm[t] = (f32x4){fminf(r.x, d.x), fminf(r.y, d.y), fminf(r.z, d.z), fminf(r.w, d.w)};
            cm = fminf(cm, fminf(fminf(d.x, d.y), fminf(d.z, d.w)));
        }
        cm = fminf(cm, __shfl_xor(cm, 16));
        cm = fminf(cm, __shfl_xor(cm, 32));
        if (lane < 16) {
            int j = wid * BC + step * 16 + c15;
            colw[j] = fminf(colw[j], cm);
        }
    }

    // ---- row mins: butterfly across the 16 col-lanes, vector store ----
#pragma unroll
    for (int t = 0; t < 8; t++) {
        f32x4 v = rm[t];
#pragma unroll
        for (int m = 1; m < 16; m <<= 1) {
            v.x = fminf(v.x, __shfl_xor(v.x, m));
            v.y = fminf(v.y, __shfl_xor(v.y, m));
            v.z = fminf(v.z, __shfl_xor(v.z, m));
            v.w = fminf(v.w, __shfl_xor(v.w, m));
        }
        if ((lane & 15) == 0) {
            int grow = rc * BR + wrow0 + t * 16 + 4 * (lane >> 4);
            *(f32x4*)(rowPart + (size_t)cc * N_PTS + grow) = v;
        }
    }

    // ---- col mins: merge 4 waves' colw ----
    __syncthreads();
    for (int c = tid; c < BC; c += TPB) {
        float v = fminf(fminf(colw[c], colw[BC + c]), fminf(colw[2 * BC + c], colw[3 * BC + c]));
        colPart[(size_t)rc * N_PTS + cc * BC + c] = v;
    }
}

__global__ __launch_bounds__(TPB) void reduce_kernel(const float* __restrict__ pred,
                                                     const float* __restrict__ gt,
                                                     const float* __restrict__ rowPart,
                                                     const float* __restrict__ colPart,
                                                     float2* __restrict__ blockPart,
                                                     unsigned* __restrict__ counter,
                                                     float* __restrict__ out) {
    __shared__ float sD[4], sC[4];
    __shared__ int isLast;
    int tid = threadIdx.x;
    int lane = tid & 63;
    int wid = tid >> 6;
    int i = blockIdx.x * TPB + tid;          // 0 .. 2N-1

    const float* P = (i < N_PTS) ? (rowPart + i) : (colPart + (i - N_PTS));
    float f = INF;
#pragma unroll
    for (int c2 = 0; c2 < 32; c2++) f = fminf(f, P[(size_t)c2 * N_PTS]);
    float d = sqrtf(fmaxf(2.0f * f, 0.0f));

    float csum = 0.0f;
    if (i < N_PTS) {
        size_t b = (size_t)i * 6 + 3;
        csum = fabsf(pred[b] - gt[b]) + fabsf(pred[b + 1] - gt[b + 1]) + fabsf(pred[b + 2] - gt[b + 2]);
    }

#pragma unroll
    for (int o = 32; o; o >>= 1) { d += __shfl_down(d, o); csum += __shfl_down(csum, o); }
    if (lane == 0) { sD[wid] = d; sC[wid] = csum; }
    if (tid == 0) isLast = 0;
    __syncthreads();
    if (tid == 0) {
        float D = sD[0] + sD[1] + sD[2] + sD[3];
        float C = sC[0] + sC[1] + sC[2] + sC[3];
        blockPart[blockIdx.x] = make_float2(D, C);
        __threadfence();
        unsigned old = atomicAdd(counter, 1u);
        // ws is poisoned to 0xAA each launch (hedge: also accept zero-init)
        if (old == 0xAAAAAAAAu + 127u || old == 127u) isLast = 1;
    }
    __syncthreads();
    if (isLast) {
        __threadfence();
        float D = 0.0f, C = 0.0f;
        if (tid < 128) { float2 bp = blockPart[tid]; D = bp.x; C = bp.y; }
#pragma unroll
        for (int o = 32; o; o >>= 1) { D += __shfl_down(D, o); C += __shfl_down(C, o); }
        if (tid < 128 && lane == 0) { sD[wid] = D; sC[wid] = C; }
        __syncthreads();
        if (tid == 0) {
            float DD = sD[0] + sD[1], CC = sC[0] + sC[1];
            out[0] = DD * (1.0f / N_PTS) + 0.1f * CC * (1.0f / (3.0f * N_PTS));
        }
    }
}

extern "C" void kernel_launch(void* const* d_in, const int* in_sizes, int n_in,
                              void* d_out, int out_size, void* d_ws, size_t ws_size,
                              hipStream_t stream) {
    const float* pred = (const float*)d_in[0];
    const float* gt = (const float*)d_in[1];
    char* base = (char*)d_ws;
    unsigned* counter = (unsigned*)base;
    float* rowPart = (float*)(base + 256);
    float* colPart = rowPart + (size_t)NCC * N_PTS;
    float2* blockPart = (float2*)(colPart + (size_t)NRC * N_PTS);
    float* out = (float*)d_out;

    pairs_mfma<<<NRC * NCC, TPB, 0, stream>>>(pred, gt, rowPart, colPart);
    reduce_kernel<<<2 * N_PTS / TPB, TPB, 0, stream>>>(pred, gt, rowPart, colPart,
                                                       blockPart, counter, out);
}

// Round 5
// 88.906 us; speedup vs baseline: 1.2447x; 1.2447x over previous
//
#include <hip/hip_runtime.h>
#include <math.h>

#define N_PTS 16384
#define TPB 256
#define QB 256                   // queries per block
#define TB 512                   // targets per block
#define NQC (2 * N_PTS / QB)     // 128 query chunks (combined pred+gt query space)
#define NTC (N_PTS / TB)         // 32 target chunks
#define INF 3.0e38f

typedef short bf16x8 __attribute__((ext_vector_type(8)));
typedef float f32x16 __attribute__((ext_vector_type(16)));

__device__ __forceinline__ unsigned short bf16_rne(float x) {
    unsigned u = __float_as_uint(x);
    unsigned r = u + 0x7FFFu + ((u >> 16) & 1u);
    return (unsigned short)(r >> 16);
}
__device__ __forceinline__ float ubf(unsigned short h) {
    return __uint_as_float(((unsigned)h) << 16);
}

// K-slot layout (K=16, mfma_f32_32x32x16_bf16), D = |p-g|^2/2 with C=0:
//  slots 0-2 : A=-ph      B=gh        slots 3-5 : A=-pl  B=gh
//  slots 6-8 : A=-ph      B=gl        slots 9-11: A=-pl  B=gl
//  slot 12   : A=1 B=wh   slot 13: A=1 B=wl   (w=|g|^2/2 split)
//  slot 14   : A=nh B=1   slot 15: A=nl B=1   (n=|p|^2/2 split)

__device__ __forceinline__ void packA(const float* __restrict__ p, unsigned short* dst) {
    float x = p[0], y = p[1], z = p[2];
    unsigned short xh = bf16_rne(x), yh = bf16_rne(y), zh = bf16_rne(z);
    unsigned short xl = bf16_rne(x - ubf(xh)), yl = bf16_rne(y - ubf(yh)), zl = bf16_rne(z - ubf(zh));
    float nrm = 0.5f * (x * x + y * y + z * z);
    unsigned short nh = bf16_rne(nrm), nl = bf16_rne(nrm - ubf(nh));
    const unsigned short ONE = 0x3F80u, S = 0x8000u;
    union { unsigned short u[16]; bf16x8 v[2]; } pk;
    pk.u[0] = xh ^ S; pk.u[1] = yh ^ S; pk.u[2] = zh ^ S;
    pk.u[3] = xl ^ S; pk.u[4] = yl ^ S; pk.u[5] = zl ^ S;
    pk.u[6] = xh ^ S; pk.u[7] = yh ^ S; pk.u[8] = zh ^ S;
    pk.u[9] = xl ^ S; pk.u[10] = yl ^ S; pk.u[11] = zl ^ S;
    pk.u[12] = ONE; pk.u[13] = ONE; pk.u[14] = nh; pk.u[15] = nl;
    *(bf16x8*)&dst[0] = pk.v[0];
    *(bf16x8*)&dst[8] = pk.v[1];
}

__device__ __forceinline__ void packB(const float* __restrict__ p, unsigned short* dst) {
    float x = p[0], y = p[1], z = p[2];
    unsigned short xh = bf16_rne(x), yh = bf16_rne(y), zh = bf16_rne(z);
    unsigned short xl = bf16_rne(x - ubf(xh)), yl = bf16_rne(y - ubf(yh)), zl = bf16_rne(z - ubf(zh));
    float w = 0.5f * (x * x + y * y + z * z);
    unsigned short wh = bf16_rne(w), wl = bf16_rne(w - ubf(wh));
    const unsigned short ONE = 0x3F80u;
    union { unsigned short u[16]; bf16x8 v[2]; } pk;
    pk.u[0] = xh; pk.u[1] = yh; pk.u[2] = zh;
    pk.u[3] = xh; pk.u[4] = yh; pk.u[5] = zh;
    pk.u[6] = xl; pk.u[7] = yl; pk.u[8] = zl;
    pk.u[9] = xl; pk.u[10] = yl; pk.u[11] = zl;
    pk.u[12] = wh; pk.u[13] = wl; pk.u[14] = ONE; pk.u[15] = ONE;
    *(bf16x8*)&dst[0] = pk.v[0];
    *(bf16x8*)&dst[8] = pk.v[1];
}

// smem union: pack phase {A:[256][16]us @0, B:[512][16]us @8192} = 24576 B
//             epilogue   {epi:[4][64][33]f}                     = 33792 B
#define SMEM_BYTES 33792

__global__ __launch_bounds__(TPB) void pairs32(const float* __restrict__ pred,
                                               const float* __restrict__ gt,
                                               float* __restrict__ minPart) {
    __shared__ __align__(16) char smem[SMEM_BYTES];
    unsigned short* ldsA = (unsigned short*)smem;            // [QB][16]
    unsigned short* ldsB = (unsigned short*)(smem + 8192);   // [TB][16]

    int tid = threadIdx.x;
    int lane = tid & 63, w = tid >> 6;
    int l31 = lane & 31, lh = lane >> 5;
    int qc = blockIdx.x & (NQC - 1);
    int tc = blockIdx.x >> 7;
    int q0g = qc * QB;                 // global combined query base [0, 2N)

    const float* qArr; const float* tArr; int q0;
    if (q0g < N_PTS) { qArr = pred; tArr = gt; q0 = q0g; }
    else             { qArr = gt; tArr = pred; q0 = q0g - N_PTS; }
    int tb = tc * TB;

    // ---- in-block pack: 256 A rows (1/thread), 512 B rows (2/thread) ----
    packA(qArr + (size_t)(q0 + tid) * 6, &ldsA[tid * 16]);
    packB(tArr + (size_t)(tb + tid) * 6, &ldsB[tid * 16]);
    packB(tArr + (size_t)(tb + TPB + tid) * 6, &ldsB[(TPB + tid) * 16]);
    __syncthreads();

    // ---- A fragments: wave w owns block rows w*64 .. w*64+63 (2 tiles) ----
    bf16x8 a0 = *(const bf16x8*)&ldsA[(w * 64 + l31) * 16 + lh * 8];
    bf16x8 a1 = *(const bf16x8*)&ldsA[(w * 64 + 32 + l31) * 16 + lh * 8];

    f32x16 rm0, rm1, zc;
#pragma unroll
    for (int i = 0; i < 16; i++) { rm0[i] = INF; rm1[i] = INF; zc[i] = 0.0f; }

    // ---- main loop: 16 col-tiles of 32 targets ----
    for (int s = 0; s < TB / 32; s++) {
        bf16x8 b = *(const bf16x8*)&ldsB[(s * 32 + l31) * 16 + lh * 8];
        f32x16 d0 = __builtin_amdgcn_mfma_f32_32x32x16_bf16(a0, b, zc, 0, 0, 0);
        f32x16 d1 = __builtin_amdgcn_mfma_f32_32x32x16_bf16(a1, b, zc, 0, 0, 0);
#pragma unroll
        for (int i = 0; i < 16; i++) {
            rm0[i] = fminf(rm0[i], d0[i]);
            rm1[i] = fminf(rm1[i], d1[i]);
        }
    }

    // ---- epilogue: row-min via padded LDS transpose (stride 33, conflict-free) ----
    __syncthreads();   // all waves done reading ldsA/ldsB
    float* ep = (float*)smem + w * (64 * 33);
#pragma unroll
    for (int r = 0; r < 16; r++) {
        int row = (r & 3) + 8 * (r >> 2) + 4 * lh;   // C/D layout: col=lane&31
        ep[row * 33 + l31] = rm0[r];
        ep[(row + 32) * 33 + l31] = rm1[r];
    }
    __syncthreads();   // (wave-local would suffice; barrier keeps it simple/safe)
    float m = ep[lane * 33];
#pragma unroll
    for (int c = 1; c < 32; c++) m = fminf(m, ep[lane * 33 + c]);
    minPart[(size_t)tc * (2 * N_PTS) + q0g + w * 64 + lane] = m;
}

__global__ __launch_bounds__(TPB) void reduce_kernel(const float* __restrict__ pred,
                                                     const float* __restrict__ gt,
                                                     const float* __restrict__ minPart,
                                                     float2* __restrict__ blockPart,
                                                     unsigned* __restrict__ counter,
                                                     float* __restrict__ out) {
    __shared__ float sD[4], sC[4];
    __shared__ int isLast;
    int tid = threadIdx.x;
    int lane = tid & 63;
    int wid = tid >> 6;
    int i = blockIdx.x * TPB + tid;          // 0 .. 2N-1

    float f = INF;
#pragma unroll
    for (int c = 0; c < NTC; c++) f = fminf(f, minPart[(size_t)c * (2 * N_PTS) + i]);
    float d = sqrtf(fmaxf(2.0f * f, 0.0f));

    float csum = 0.0f;
    if (i < N_PTS) {
        size_t b = (size_t)i * 6 + 3;
        csum = fabsf(pred[b] - gt[b]) + fabsf(pred[b + 1] - gt[b + 1]) + fabsf(pred[b + 2] - gt[b + 2]);
    }

#pragma unroll
    for (int o = 32; o; o >>= 1) { d += __shfl_down(d, o); csum += __shfl_down(csum, o); }
    if (lane == 0) { sD[wid] = d; sC[wid] = csum; }
    if (tid == 0) isLast = 0;
    __syncthreads();
    if (tid == 0) {
        float D = sD[0] + sD[1] + sD[2] + sD[3];
        float C = sC[0] + sC[1] + sC[2] + sC[3];
        blockPart[blockIdx.x] = make_float2(D, C);
        __threadfence();
        unsigned old = atomicAdd(counter, 1u);
        // ws is poisoned to 0xAA each launch (hedge: also accept zero-init)
        if (old == 0xAAAAAAAAu + 127u || old == 127u) isLast = 1;
    }
    __syncthreads();
    if (isLast) {
        __threadfence();
        float D = 0.0f, C = 0.0f;
        if (tid < 128) { float2 bp = blockPart[tid]; D = bp.x; C = bp.y; }
#pragma unroll
        for (int o = 32; o; o >>= 1) { D += __shfl_down(D, o); C += __shfl_down(C, o); }
        if (tid < 128 && lane == 0) { sD[wid] = D; sC[wid] = C; }
        __syncthreads();
        if (tid == 0) {
            float DD = sD[0] + sD[1], CC = sC[0] + sC[1];
            out[0] = DD * (1.0f / N_PTS) + 0.1f * CC * (1.0f / (3.0f * N_PTS));
        }
    }
}

extern "C" void kernel_launch(void* const* d_in, const int* in_sizes, int n_in,
                              void* d_out, int out_size, void* d_ws, size_t ws_size,
                              hipStream_t stream) {
    const float* pred = (const float*)d_in[0];
    const float* gt = (const float*)d_in[1];
    char* base = (char*)d_ws;
    unsigned* counter = (unsigned*)base;
    float* minPart = (float*)(base + 256);                       // [NTC][2N] = 4MB
    float2* blockPart = (float2*)(base + 256 + (size_t)NTC * 2 * N_PTS * 4);
    float* out = (float*)d_out;

    pairs32<<<NQC * NTC, TPB, 0, stream>>>(pred, gt, minPart);
    reduce_kernel<<<2 * N_PTS / TPB, TPB, 0, stream>>>(pred, gt, minPart,
                                                       blockPart, counter, out);
}

// Round 6
// 80.740 us; speedup vs baseline: 1.3706x; 1.1011x over previous
//
#include <hip/hip_runtime.h>
#include <math.h>

#define N_PTS 16384
#define NQ (2 * N_PTS)           // combined query space (pred rows + gt rows)
#define TPB 512                  // 8 waves per block
#define QB 256                   // queries per block (8 waves x 32)
#define TB 1024                  // targets per chunk (32KB LDS)
#define NTC (N_PTS / TB)         // 16 target chunks
#define NQC (NQ / QB)            // 128 query chunks
#define INF 3.0e38f

typedef short bf16x8 __attribute__((ext_vector_type(8)));
typedef float f32x4 __attribute__((ext_vector_type(4)));
typedef float f32x16 __attribute__((ext_vector_type(16)));

__device__ __forceinline__ unsigned short bf16_rne(float x) {
    unsigned u = __float_as_uint(x);
    unsigned r = u + 0x7FFFu + ((u >> 16) & 1u);
    return (unsigned short)(r >> 16);
}
__device__ __forceinline__ float ubf(unsigned short h) {
    return __uint_as_float(((unsigned)h) << 16);
}

// K-slot layout (K=16), D[target,query] = |p-g|^2/2 with C=0:
//  slots 0-2 : T=gh  Q=-ph     slots 3-5 : T=gh  Q=-pl
//  slots 6-8 : T=gl  Q=-ph     slots 9-11: T=gl  Q=-pl
//  slot 12/13: T=wh/wl Q=1,1   (w=|g|^2/2 split)
//  slot 14/15: T=1,1  Q=nh/nl  (n=|p|^2/2 split)

__device__ __forceinline__ void packQ(const float* __restrict__ p, unsigned short* dst) {
    float x = p[0], y = p[1], z = p[2];
    unsigned short xh = bf16_rne(x), yh = bf16_rne(y), zh = bf16_rne(z);
    unsigned short xl = bf16_rne(x - ubf(xh)), yl = bf16_rne(y - ubf(yh)), zl = bf16_rne(z - ubf(zh));
    float nrm = 0.5f * (x * x + y * y + z * z);
    unsigned short nh = bf16_rne(nrm), nl = bf16_rne(nrm - ubf(nh));
    const unsigned short ONE = 0x3F80u, S = 0x8000u;
    union { unsigned short u[16]; bf16x8 v[2]; } pk;
    pk.u[0] = xh ^ S; pk.u[1] = yh ^ S; pk.u[2] = zh ^ S;
    pk.u[3] = xl ^ S; pk.u[4] = yl ^ S; pk.u[5] = zl ^ S;
    pk.u[6] = xh ^ S; pk.u[7] = yh ^ S; pk.u[8] = zh ^ S;
    pk.u[9] = xl ^ S; pk.u[10] = yl ^ S; pk.u[11] = zl ^ S;
    pk.u[12] = ONE; pk.u[13] = ONE; pk.u[14] = nh; pk.u[15] = nl;
    *(bf16x8*)&dst[0] = pk.v[0];
    *(bf16x8*)&dst[8] = pk.v[1];
}

__device__ __forceinline__ void packT(const float* __restrict__ p, unsigned short* dst) {
    float x = p[0], y = p[1], z = p[2];
    unsigned short xh = bf16_rne(x), yh = bf16_rne(y), zh = bf16_rne(z);
    unsigned short xl = bf16_rne(x - ubf(xh)), yl = bf16_rne(y - ubf(yh)), zl = bf16_rne(z - ubf(zh));
    float w = 0.5f * (x * x + y * y + z * z);
    unsigned short wh = bf16_rne(w), wl = bf16_rne(w - ubf(wh));
    const unsigned short ONE = 0x3F80u;
    union { unsigned short u[16]; bf16x8 v[2]; } pk;
    pk.u[0] = xh; pk.u[1] = yh; pk.u[2] = zh;
    pk.u[3] = xh; pk.u[4] = yh; pk.u[5] = zh;
    pk.u[6] = xl; pk.u[7] = yl; pk.u[8] = zl;
    pk.u[9] = xl; pk.u[10] = yl; pk.u[11] = zl;
    pk.u[12] = wh; pk.u[13] = wl; pk.u[14] = ONE; pk.u[15] = ONE;
    *(bf16x8*)&dst[0] = pk.v[0];
    *(bf16x8*)&dst[8] = pk.v[1];
}

__global__ __launch_bounds__(256) void prep_kernel(const float* __restrict__ pred,
                                                   const float* __restrict__ gt,
                                                   unsigned short* __restrict__ Qpk,
                                                   unsigned short* __restrict__ Tpk) {
    int i = blockIdx.x * 256 + threadIdx.x;   // 0..NQ-1
    const float* p = (i < N_PTS) ? (pred + (size_t)i * 6) : (gt + (size_t)(i - N_PTS) * 6);
    packQ(p, &Qpk[(size_t)i * 16]);
    packT(p, &Tpk[(size_t)i * 16]);
}

// Targets in A (rows), queries in B (cols): each lane's 16 D-regs are 16 target
// rows for ONE query column => row-min is an in-register min3 tree into qmin.
__global__ __launch_bounds__(TPB) void pairs_kernel(const unsigned short* __restrict__ Qpk,
                                                    const unsigned short* __restrict__ Tpk,
                                                    float* __restrict__ minPart) {
    __shared__ __align__(16) unsigned short ldsT[TB * 16];   // 32KB, linear [row][16]

    int tid = threadIdx.x;
    int lane = tid & 63, w = tid >> 6;
    int l31 = lane & 31, lh = lane >> 5;
    int qc = blockIdx.x & (NQC - 1);
    int tc = blockIdx.x >> 7;                 // NQC = 128
    int q0 = qc * QB;                         // [0, NQ)
    int trow0 = (q0 < N_PTS) ? (N_PTS + tc * TB) : (tc * TB);  // opposing side

    // ---- stage target chunk (32KB contiguous, coalesced, conflict-free) ----
    const f32x4* src = (const f32x4*)(Tpk + (size_t)trow0 * 16);
    f32x4* dst = (f32x4*)ldsT;
#pragma unroll
    for (int i = 0; i < (TB * 32) / 16 / TPB; i++)   // 4 iters
        dst[i * TPB + tid] = src[i * TPB + tid];

    // ---- query fragment from global (coalesced 16B/lane) ----
    bf16x8 bq = *(const bf16x8*)&Qpk[(size_t)(q0 + w * 32 + l31) * 16 + lh * 8];

    __syncthreads();

    f32x16 zc;
#pragma unroll
    for (int i = 0; i < 16; i++) zc[i] = 0.0f;

    float qmin = INF;
    const bf16x8* A = (const bf16x8*)ldsT;    // 2 frags per row
#pragma unroll 2
    for (int s = 0; s < TB / 32; s++) {
        bf16x8 a = A[(s * 32 + l31) * 2 + lh];
        f32x16 d = __builtin_amdgcn_mfma_f32_32x32x16_bf16(a, bq, zc, 0, 0, 0);
        // min3 tree: 8 fused v_min3_f32, depth 3
        float t0 = fminf(fminf(d[0], d[1]), d[2]);
        float t1 = fminf(fminf(d[3], d[4]), d[5]);
        float t2 = fminf(fminf(d[6], d[7]), d[8]);
        float t3 = fminf(fminf(d[9], d[10]), d[11]);
        float t4 = fminf(fminf(d[12], d[13]), d[14]);
        float u0 = fminf(fminf(t0, t1), t2);
        float u1 = fminf(fminf(t3, t4), d[15]);
        qmin = fminf(fminf(u0, u1), qmin);
    }

    // lanes lh=0/1 hold complementary target rows: one swap finishes the min
    qmin = fminf(qmin, __shfl_xor(qmin, 32));
    if (lh == 0)
        minPart[(size_t)tc * NQ + q0 + w * 32 + l31] = qmin;
}

__global__ __launch_bounds__(256) void reduce_kernel(const float* __restrict__ pred,
                                                     const float* __restrict__ gt,
                                                     const float* __restrict__ minPart,
                                                     float2* __restrict__ blockPart,
                                                     unsigned* __restrict__ counter,
                                                     float* __restrict__ out) {
    __shared__ float sD[4], sC[4];
    __shared__ int isLast;
    int tid = threadIdx.x;
    int lane = tid & 63;
    int wid = tid >> 6;
    int i = blockIdx.x * 256 + tid;          // 0 .. NQ-1

    float f = INF;
#pragma unroll
    for (int c = 0; c < NTC; c++) f = fminf(f, minPart[(size_t)c * NQ + i]);
    float d = sqrtf(fmaxf(2.0f * f, 0.0f));

    float csum = 0.0f;
    if (i < N_PTS) {
        size_t b = (size_t)i * 6 + 3;
        csum = fabsf(pred[b] - gt[b]) + fabsf(pred[b + 1] - gt[b + 1]) + fabsf(pred[b + 2] - gt[b + 2]);
    }

#pragma unroll
    for (int o = 32; o; o >>= 1) { d += __shfl_down(d, o); csum += __shfl_down(csum, o); }
    if (lane == 0) { sD[wid] = d; sC[wid] = csum; }
    if (tid == 0) isLast = 0;
    __syncthreads();
    if (tid == 0) {
        float D = sD[0] + sD[1] + sD[2] + sD[3];
        float C = sC[0] + sC[1] + sC[2] + sC[3];
        blockPart[blockIdx.x] = make_float2(D, C);
        __threadfence();
        unsigned old = atomicAdd(counter, 1u);
        // ws is poisoned to 0xAA each launch (hedge: also accept zero-init)
        if (old == 0xAAAAAAAAu + 127u || old == 127u) isLast = 1;
    }
    __syncthreads();
    if (isLast) {
        __threadfence();
        float D = 0.0f, C = 0.0f;
        if (tid < 128) { float2 bp = blockPart[tid]; D = bp.x; C = bp.y; }
#pragma unroll
        for (int o = 32; o; o >>= 1) { D += __shfl_down(D, o); C += __shfl_down(C, o); }
        if (tid < 128 && lane == 0) { sD[wid] = D; sC[wid] = C; }
        __syncthreads();
        if (tid == 0) {
            float DD = sD[0] + sD[1], CC = sC[0] + sC[1];
            out[0] = DD * (1.0f / N_PTS) + 0.1f * CC * (1.0f / (3.0f * N_PTS));
        }
    }
}

extern "C" void kernel_launch(void* const* d_in, const int* in_sizes, int n_in,
                              void* d_out, int out_size, void* d_ws, size_t ws_size,
                              hipStream_t stream) {
    const float* pred = (const float*)d_in[0];
    const float* gt = (const float*)d_in[1];
    char* base = (char*)d_ws;
    unsigned* counter = (unsigned*)base;
    float2* blockPart = (float2*)(base + 256);                      // 1KB
    unsigned short* Qpk = (unsigned short*)(base + 4096);           // NQ*32B = 1MB
    unsigned short* Tpk = (unsigned short*)(base + 4096 + (size_t)NQ * 32);
    float* minPart = (float*)(base + 4096 + 2 * (size_t)NQ * 32);   // NTC*NQ*4 = 2MB
    float* out = (float*)d_out;

    prep_kernel<<<NQ / 256, 256, 0, stream>>>(pred, gt, Qpk, Tpk);
    pairs_kernel<<<NQC * NTC, TPB, 0, stream>>>(Qpk, Tpk, minPart);
    reduce_kernel<<<NQ / 256, 256, 0, stream>>>(pred, gt, minPart, blockPart, counter, out);
}

// Round 7
// 78.600 us; speedup vs baseline: 1.4079x; 1.0272x over previous
//
#include <hip/hip_runtime.h>
#include <math.h>

#define N_PTS 16384
#define NQ (2 * N_PTS)           // combined query space (pred rows + gt rows)
#define TPB 512                  // 8 waves per block
#define QB 512                   // queries per block (8 waves x 32 x 2 frags)
#define TB 1024                  // targets per chunk (32KB LDS)
#define NTC (N_PTS / TB)         // 16 target chunks
#define NQC (NQ / QB)            // 64 query chunks
#define INF 3.0e38f

typedef short bf16x8 __attribute__((ext_vector_type(8)));
typedef float f32x4 __attribute__((ext_vector_type(4)));
typedef float f32x16 __attribute__((ext_vector_type(16)));

__device__ __forceinline__ unsigned short bf16_rne(float x) {
    unsigned u = __float_as_uint(x);
    unsigned r = u + 0x7FFFu + ((u >> 16) & 1u);
    return (unsigned short)(r >> 16);
}
__device__ __forceinline__ float ubf(unsigned short h) {
    return __uint_as_float(((unsigned)h) << 16);
}
__device__ __forceinline__ unsigned enc_key(float f) {
    unsigned b = __float_as_uint(f);
    return (b & 0x80000000u) ? ~b : (b | 0x80000000u);
}
__device__ __forceinline__ float dec_key(unsigned k) {
    unsigned b = (k & 0x80000000u) ? (k ^ 0x80000000u) : ~k;
    return __uint_as_float(b);
}

// K-slot layout (K=16), D[target,query] = |p-g|^2/2 with C=0:
//  slots 0-2 : T=gh  Q=-ph     slots 3-5 : T=gh  Q=-pl
//  slots 6-8 : T=gl  Q=-ph     slots 9-11: T=gl  Q=-pl
//  slot 12/13: T=wh/wl Q=1,1   (w=|g|^2/2 split)
//  slot 14/15: T=1,1  Q=nh/nl  (n=|p|^2/2 split)

__device__ __forceinline__ void packQ(const float* __restrict__ p, unsigned short* dst) {
    float x = p[0], y = p[1], z = p[2];
    unsigned short xh = bf16_rne(x), yh = bf16_rne(y), zh = bf16_rne(z);
    unsigned short xl = bf16_rne(x - ubf(xh)), yl = bf16_rne(y - ubf(yh)), zl = bf16_rne(z - ubf(zh));
    float nrm = 0.5f * (x * x + y * y + z * z);
    unsigned short nh = bf16_rne(nrm), nl = bf16_rne(nrm - ubf(nh));
    const unsigned short ONE = 0x3F80u, S = 0x8000u;
    union { unsigned short u[16]; bf16x8 v[2]; } pk;
    pk.u[0] = xh ^ S; pk.u[1] = yh ^ S; pk.u[2] = zh ^ S;
    pk.u[3] = xl ^ S; pk.u[4] = yl ^ S; pk.u[5] = zl ^ S;
    pk.u[6] = xh ^ S; pk.u[7] = yh ^ S; pk.u[8] = zh ^ S;
    pk.u[9] = xl ^ S; pk.u[10] = yl ^ S; pk.u[11] = zl ^ S;
    pk.u[12] = ONE; pk.u[13] = ONE; pk.u[14] = nh; pk.u[15] = nl;
    *(bf16x8*)&dst[0] = pk.v[0];
    *(bf16x8*)&dst[8] = pk.v[1];
}

__device__ __forceinline__ void packT(const float* __restrict__ p, unsigned short* dst) {
    float x = p[0], y = p[1], z = p[2];
    unsigned short xh = bf16_rne(x), yh = bf16_rne(y), zh = bf16_rne(z);
    unsigned short xl = bf16_rne(x - ubf(xh)), yl = bf16_rne(y - ubf(yh)), zl = bf16_rne(z - ubf(zh));
    float w = 0.5f * (x * x + y * y + z * z);
    unsigned short wh = bf16_rne(w), wl = bf16_rne(w - ubf(wh));
    const unsigned short ONE = 0x3F80u;
    union { unsigned short u[16]; bf16x8 v[2]; } pk;
    pk.u[0] = xh; pk.u[1] = yh; pk.u[2] = zh;
    pk.u[3] = xh; pk.u[4] = yh; pk.u[5] = zh;
    pk.u[6] = xl; pk.u[7] = yl; pk.u[8] = zl;
    pk.u[9] = xl; pk.u[10] = yl; pk.u[11] = zl;
    pk.u[12] = wh; pk.u[13] = wl; pk.u[14] = ONE; pk.u[15] = ONE;
    *(bf16x8*)&dst[0] = pk.v[0];
    *(bf16x8*)&dst[8] = pk.v[1];
}

__global__ __launch_bounds__(256) void prep_kernel(const float* __restrict__ pred,
                                                   const float* __restrict__ gt,
                                                   unsigned short* __restrict__ Qpk,
                                                   unsigned short* __restrict__ Tpk,
                                                   unsigned* __restrict__ minKey,
                                                   float* __restrict__ colorPart) {
    int i = blockIdx.x * 256 + threadIdx.x;   // 0..NQ-1
    const float* p = (i < N_PTS) ? (pred + (size_t)i * 6) : (gt + (size_t)(i - N_PTS) * 6);
    packQ(p, &Qpk[(size_t)i * 16]);
    packT(p, &Tpk[(size_t)i * 16]);
    minKey[i] = 0xFFFFFFFFu;

    float csum = 0.0f;
    if (i < N_PTS) {
        size_t b = (size_t)i * 6 + 3;
        csum = fabsf(pred[b] - gt[b]) + fabsf(pred[b + 1] - gt[b + 1]) + fabsf(pred[b + 2] - gt[b + 2]);
    }
#pragma unroll
    for (int o = 32; o; o >>= 1) csum += __shfl_down(csum, o);
    if ((threadIdx.x & 63) == 0) colorPart[i >> 6] = csum;   // [0, NQ/64)
}

// Targets in A (rows), queries in B (cols): each lane's 16 D-regs are 16 target
// rows for ONE query column => row-min is an in-register min3 tree.
// One A-frag ds_read feeds TWO MFMAs (two query fragments per wave).
__global__ __launch_bounds__(TPB) void pairs_kernel(const unsigned short* __restrict__ Qpk,
                                                    const unsigned short* __restrict__ Tpk,
                                                    unsigned* __restrict__ minKey) {
    __shared__ __align__(16) unsigned short ldsT[TB * 16];   // 32KB, linear [row][16]

    int tid = threadIdx.x;
    int lane = tid & 63, w = tid >> 6;
    int l31 = lane & 31, lh = lane >> 5;
    int qc = blockIdx.x & (NQC - 1);
    int tc = blockIdx.x >> 6;                 // NQC = 64
    int q0 = qc * QB;                         // [0, NQ)
    int trow0 = (q0 < N_PTS) ? (N_PTS + tc * TB) : (tc * TB);  // opposing side

    // ---- stage target chunk (32KB contiguous, coalesced, conflict-free) ----
    const f32x4* src = (const f32x4*)(Tpk + (size_t)trow0 * 16);
    f32x4* dst = (f32x4*)ldsT;
#pragma unroll
    for (int i = 0; i < (TB * 32) / 16 / TPB; i++)   // 4 iters
        dst[i * TPB + tid] = src[i * TPB + tid];

    // ---- two query fragments per wave (coalesced 16B/lane) ----
    bf16x8 bq0 = *(const bf16x8*)&Qpk[(size_t)(q0 + w * 32 + l31) * 16 + lh * 8];
    bf16x8 bq1 = *(const bf16x8*)&Qpk[(size_t)(q0 + 256 + w * 32 + l31) * 16 + lh * 8];

    __syncthreads();

    f32x16 zc;
#pragma unroll
    for (int i = 0; i < 16; i++) zc[i] = 0.0f;

    float qmin0 = INF, qmin1 = INF;
    const bf16x8* A = (const bf16x8*)ldsT;    // 2 frags per row
#pragma unroll 2
    for (int s = 0; s < TB / 32; s++) {
        bf16x8 a = A[(s * 32 + l31) * 2 + lh];
        f32x16 d0 = __builtin_amdgcn_mfma_f32_32x32x16_bf16(a, bq0, zc, 0, 0, 0);
        f32x16 d1 = __builtin_amdgcn_mfma_f32_32x32x16_bf16(a, bq1, zc, 0, 0, 0);
        {
            float t0 = fminf(fminf(d0[0], d0[1]), d0[2]);
            float t1 = fminf(fminf(d0[3], d0[4]), d0[5]);
            float t2 = fminf(fminf(d0[6], d0[7]), d0[8]);
            float t3 = fminf(fminf(d0[9], d0[10]), d0[11]);
            float t4 = fminf(fminf(d0[12], d0[13]), d0[14]);
            float u0 = fminf(fminf(t0, t1), t2);
            float u1 = fminf(fminf(t3, t4), d0[15]);
            qmin0 = fminf(fminf(u0, u1), qmin0);
        }
        {
            float t0 = fminf(fminf(d1[0], d1[1]), d1[2]);
            float t1 = fminf(fminf(d1[3], d1[4]), d1[5]);
            float t2 = fminf(fminf(d1[6], d1[7]), d1[8]);
            float t3 = fminf(fminf(d1[9], d1[10]), d1[11]);
            float t4 = fminf(fminf(d1[12], d1[13]), d1[14]);
            float u0 = fminf(fminf(t0, t1), t2);
            float u1 = fminf(fminf(t3, t4), d1[15]);
            qmin1 = fminf(fminf(u0, u1), qmin1);
        }
    }

    qmin0 = fminf(qmin0, __shfl_xor(qmin0, 32));
    qmin1 = fminf(qmin1, __shfl_xor(qmin1, 32));
    if (lh == 0) {
        atomicMin(&minKey[q0 + w * 32 + l31], enc_key(qmin0));
        atomicMin(&minKey[q0 + 256 + w * 32 + l31], enc_key(qmin1));
    }
}

__global__ __launch_bounds__(1024) void finish_kernel(const unsigned* __restrict__ minKey,
                                                      const float* __restrict__ colorPart,
                                                      float* __restrict__ out) {
    __shared__ float sD[16], sC[16];
    int tid = threadIdx.x;
    int lane = tid & 63, w = tid >> 6;

    float dsum = 0.0f;
#pragma unroll
    for (int k = 0; k < NQ / 1024; k++) {
        float f = dec_key(minKey[tid + k * 1024]);
        dsum += sqrtf(fmaxf(2.0f * f, 0.0f));
    }
    float csum = (tid < N_PTS / 64) ? colorPart[tid] : 0.0f;

#pragma unroll
    for (int o = 32; o; o >>= 1) { dsum += __shfl_down(dsum, o); csum += __shfl_down(csum, o); }
    if (lane == 0) { sD[w] = dsum; sC[w] = csum; }
    __syncthreads();
    if (tid == 0) {
        float D = 0.0f, C = 0.0f;
#pragma unroll
        for (int i = 0; i < 16; i++) { D += sD[i]; C += sC[i]; }
        out[0] = D * (1.0f / N_PTS) + 0.1f * C * (1.0f / (3.0f * N_PTS));
    }
}

extern "C" void kernel_launch(void* const* d_in, const int* in_sizes, int n_in,
                              void* d_out, int out_size, void* d_ws, size_t ws_size,
                              hipStream_t stream) {
    const float* pred = (const float*)d_in[0];
    const float* gt = (const float*)d_in[1];
    char* base = (char*)d_ws;
    unsigned* minKey = (unsigned*)base;                          // NQ*4 = 128KB
    float* colorPart = (float*)(base + (size_t)NQ * 4);          // 2KB
    unsigned short* Qpk = (unsigned short*)(base + 192 * 1024);  // NQ*32B = 1MB
    unsigned short* Tpk = Qpk + (size_t)NQ * 16;                 // 1MB
    float* out = (float*)d_out;

    prep_kernel<<<NQ / 256, 256, 0, stream>>>(pred, gt, Qpk, Tpk, minKey, colorPart);
    pairs_kernel<<<NQC * NTC, TPB, 0, stream>>>(Qpk, Tpk, minKey);
    finish_kernel<<<1, 1024, 0, stream>>>(minKey, colorPart, out);
}